// Round 1
// baseline (51.865 us; speedup 1.0000x reference)
//
#include <hip/hip_runtime.h>

#define B 4
#define NQ 512
#define NK 512
#define D 128
#define H 32

// tanh(x) = (e^{2x}-1)/(e^{2x}+1) = 1 - 2/(e^{2x}+1)  (exact identity; native exp+rcp)
// Large |x| handled by fp32 inf/0 semantics: e=inf -> rcp=0 -> 1; e=0 -> -1.
__device__ __forceinline__ float tanh_fast(float x) {
    float e = __expf(2.0f * x);
    return 1.0f - 2.0f * __builtin_amdgcn_rcpf(e + 1.0f);
}

// Computes kh = keys @ Wk + b1   (B*NK rows)  and  qh = queries @ Wq  (B*NQ rows).
// 8 rows per block, 256 threads: thread = (row_in_block, h).
__global__ __launch_bounds__(256) void proj_kernel(
    const float* __restrict__ keys, const float* __restrict__ queries,
    const float* __restrict__ Wk, const float* __restrict__ Wq,
    const float* __restrict__ b1,
    float* __restrict__ kh, float* __restrict__ qh)
{
    __shared__ float xs[8][D];
    const int tid = threadIdx.x;
    const int r0 = blockIdx.x * 8;              // global row base; B*NK % 8 == 0 so no straddle
    const bool is_q = (r0 >= B * NK);
    const float* __restrict__ X = is_q ? (queries + (size_t)(r0 - B * NK) * D)
                                       : (keys + (size_t)r0 * D);
    const float* __restrict__ W = is_q ? Wq : Wk;
    float* __restrict__ out = is_q ? (qh + (size_t)(r0 - B * NK) * H)
                                   : (kh + (size_t)r0 * H);

    // Stage 8x128 floats (4 KB) into LDS: 256 float4, one per thread.
    reinterpret_cast<float4*>(&xs[0][0])[tid] =
        reinterpret_cast<const float4*>(X)[tid];
    __syncthreads();

    const int lr = tid >> 5;   // 0..7
    const int h  = tid & 31;   // 0..31
    float acc = 0.f;
    #pragma unroll 16
    for (int d = 0; d < D; ++d)
        acc = fmaf(xs[lr][d], W[d * H + h], acc);   // W read coalesced across h
    if (!is_q) acc += b1[h];                        // fold b1 into kh only
    out[lr * H + h] = acc;
}

// One block per (b,q). 256 threads.
__global__ __launch_bounds__(256) void attend_kernel(
    const float* __restrict__ keys,
    const float* __restrict__ kh,     // b1 already folded in
    const float* __restrict__ qh,
    const float* __restrict__ w2,
    float* __restrict__ outp)
{
    __shared__ float qh_s[H];
    __shared__ float w2_s[H];
    __shared__ float ex[NK];
    __shared__ float red[256];
    __shared__ float part[2][D];

    const int tid = threadIdx.x;
    const int b = blockIdx.x >> 9;    // / NQ
    const int q = blockIdx.x & (NQ - 1);

    if (tid < H)            qh_s[tid]     = qh[((size_t)b * NQ + q) * H + tid];
    else if (tid < 2 * H)   w2_s[tid - H] = w2[tid - H];
    __syncthreads();

    // ---- logits for k = tid and k = tid + 256 (b2 omitted: softmax shift-invariant)
    float l[2];
    #pragma unroll
    for (int j = 0; j < 2; ++j) {
        const int k = tid + j * 256;
        const float4* kr = reinterpret_cast<const float4*>(kh + ((size_t)b * NK + k) * H);
        float acc = 0.f;
        #pragma unroll
        for (int h4 = 0; h4 < H / 4; ++h4) {
            float4 v = kr[h4];
            const int h = h4 * 4;
            acc = fmaf(w2_s[h + 0], tanh_fast(qh_s[h + 0] + v.x), acc);
            acc = fmaf(w2_s[h + 1], tanh_fast(qh_s[h + 1] + v.y), acc);
            acc = fmaf(w2_s[h + 2], tanh_fast(qh_s[h + 2] + v.z), acc);
            acc = fmaf(w2_s[h + 3], tanh_fast(qh_s[h + 3] + v.w), acc);
        }
        l[j] = acc;
    }

    // ---- block max
    red[tid] = fmaxf(l[0], l[1]);
    __syncthreads();
    for (int s = 128; s > 0; s >>= 1) {
        if (tid < s) red[tid] = fmaxf(red[tid], red[tid + s]);
        __syncthreads();
    }
    const float m = red[0];
    __syncthreads();

    // ---- unnormalized exps + block sum
    const float e0 = __expf(l[0] - m);
    const float e1 = __expf(l[1] - m);
    ex[tid]       = e0;
    ex[tid + 256] = e1;
    red[tid] = e0 + e1;
    __syncthreads();
    for (int s = 128; s > 0; s >>= 1) {
        if (tid < s) red[tid] += red[tid + s];
        __syncthreads();
    }
    const float inv = 1.0f / red[0];

    // ---- context: thread (half, d) accumulates over 256 keys; coalesced on d
    const int d    = tid & (D - 1);
    const int half = tid >> 7;
    const float* kp = keys + ((size_t)b * NK + half * 256) * D + d;
    float acc = 0.f;
    #pragma unroll 4
    for (int k = 0; k < 256; ++k)
        acc = fmaf(ex[half * 256 + k], kp[(size_t)k * D], acc);
    part[half][d] = acc;
    __syncthreads();
    if (tid < D)
        outp[((size_t)b * NQ + q) * D + tid] = (part[0][tid] + part[1][tid]) * inv;
}

extern "C" void kernel_launch(void* const* d_in, const int* in_sizes, int n_in,
                              void* d_out, int out_size, void* d_ws, size_t ws_size,
                              hipStream_t stream) {
    const float* keys    = (const float*)d_in[0];
    const float* queries = (const float*)d_in[1];
    const float* Wk      = (const float*)d_in[2];
    const float* Wq      = (const float*)d_in[3];
    const float* b1      = (const float*)d_in[4];
    const float* w2      = (const float*)d_in[5];
    // d_in[6] = b2: dropped (softmax shift-invariant)
    float* out = (float*)d_out;

    float* kh = (float*)d_ws;                    // B*NK*H floats
    float* qh = kh + (size_t)B * NK * H;         // B*NQ*H floats

    const int proj_blocks = (B * NK + B * NQ) / 8;   // 512
    proj_kernel<<<proj_blocks, 256, 0, stream>>>(keys, queries, Wk, Wq, b1, kh, qh);
    attend_kernel<<<B * NQ, 256, 0, stream>>>(keys, kh, qh, w2, out);
}

// Round 2
// 30.562 us; speedup vs baseline: 1.6970x; 1.6970x over previous
//
#include <hip/hip_runtime.h>

#define B 4
#define NQ 512
#define NK 512
#define D 128
#define H 32
#define G 4                              // queries per attend block
#define PS 2.8853900817779268f           // 2*log2(e)

__device__ __forceinline__ float rcp_f(float x)  { return __builtin_amdgcn_rcpf(x); }
__device__ __forceinline__ float exp2_f(float x) { return __builtin_amdgcn_exp2f(x); }

__device__ __forceinline__ void fma4(float4& a, const float4& v, float s) {
    a.x = fmaf(s, v.x, a.x);
    a.y = fmaf(s, v.y, a.y);
    a.z = fmaf(s, v.z, a.z);
    a.w = fmaf(s, v.w, a.w);
}

// kh_pre = PS*(keys@Wk + b1)  (B*NK rows),  qh_pre = PS*(queries@Wq)  (B*NQ rows).
// Pre-scaling by 2*log2(e) lets attend use v_exp (exp2) with a single add.
__global__ __launch_bounds__(256) void proj_kernel(
    const float* __restrict__ keys, const float* __restrict__ queries,
    const float* __restrict__ Wk, const float* __restrict__ Wq,
    const float* __restrict__ b1,
    float* __restrict__ kh, float* __restrict__ qh)
{
    __shared__ float xs[8][D];
    const int tid = threadIdx.x;
    const int r0 = blockIdx.x * 8;
    const bool is_q = (r0 >= B * NK);
    const float* __restrict__ X = is_q ? (queries + (size_t)(r0 - B * NK) * D)
                                       : (keys + (size_t)r0 * D);
    const float* __restrict__ W = is_q ? Wq : Wk;
    float* __restrict__ out = is_q ? (qh + (size_t)(r0 - B * NK) * H)
                                   : (kh + (size_t)r0 * H);

    reinterpret_cast<float4*>(&xs[0][0])[tid] =
        reinterpret_cast<const float4*>(X)[tid];
    __syncthreads();

    const int lr = tid >> 5;
    const int h  = tid & 31;
    float acc = 0.f;
    #pragma unroll 16
    for (int d = 0; d < D; ++d)
        acc = fmaf(xs[lr][d], W[d * H + h], acc);
    if (!is_q) acc += b1[h];
    out[lr * H + h] = acc * PS;
}

// One block per (b, group of G=4 queries). 256 threads = 4 waves.
// Phase 1: wave w computes logits+softmax for q = q0+w, entirely in registers,
//          writes normalized weights to LDS ex_t[k][g].
// Phase 2: thread (dg 0..31, kp 0..7) accumulates context over its 64-key
//          partition for all 4 queries; each keys element read exactly once/block.
__global__ __launch_bounds__(256) void attend_kernel(
    const float* __restrict__ keys,
    const float* __restrict__ kh,     // pre-scaled, b1 folded in
    const float* __restrict__ qh,     // pre-scaled
    const float* __restrict__ w2,
    float* __restrict__ outp)
{
    __shared__ float ex_t[NK][G];     // 8 KB  [k][g], one float4 per k
    __shared__ float acc_s[8][G][D];  // 16 KB partials per k-partition

    const int tid  = threadIdx.x;
    const int lane = tid & 63;
    const int w    = tid >> 6;        // wave id == query index in group
    const int bq   = blockIdx.x;      // 0..511
    const int b    = bq >> 7;
    const int q0   = (bq & 127) * G;

    // ---- uniforms in registers: w2p[h] = -PS*w2[h], qv[h] = qh_pre row
    float w2p[H], qv[H];
    {
        const float4* w4 = reinterpret_cast<const float4*>(w2);
        const float4* q4 = reinterpret_cast<const float4*>(
            qh + ((size_t)b * NQ + q0 + w) * H);
        #pragma unroll
        for (int i = 0; i < H / 4; ++i) {
            float4 a = w4[i], c = q4[i];
            w2p[4*i+0] = -PS * a.x;  qv[4*i+0] = c.x;
            w2p[4*i+1] = -PS * a.y;  qv[4*i+1] = c.y;
            w2p[4*i+2] = -PS * a.z;  qv[4*i+2] = c.z;
            w2p[4*i+3] = -PS * a.w;  qv[4*i+3] = c.w;
        }
    }

    // ---- phase 1: logits (times log2e, constant term dropped) for k = lane + 64j
    // tanh(x) = 1 - 2*rcp(1 + exp2(PS*x)); logit' = sum_h w2p[h]*rcp(1+exp2(s_h)) + const
    float l[8];
    const float* khb = kh + (size_t)b * NK * H;
    #pragma unroll
    for (int j = 0; j < 8; ++j) {
        const float4* kr = reinterpret_cast<const float4*>(
            khb + (size_t)(64 * j + lane) * H);
        float a0 = 0.f, a1 = 0.f;
        #pragma unroll
        for (int h4 = 0; h4 < H / 4; ++h4) {
            float4 v = kr[h4];
            const int h = 4 * h4;
            a0 = fmaf(w2p[h+0], rcp_f(1.f + exp2_f(qv[h+0] + v.x)), a0);
            a1 = fmaf(w2p[h+1], rcp_f(1.f + exp2_f(qv[h+1] + v.y)), a1);
            a0 = fmaf(w2p[h+2], rcp_f(1.f + exp2_f(qv[h+2] + v.z)), a0);
            a1 = fmaf(w2p[h+3], rcp_f(1.f + exp2_f(qv[h+3] + v.w)), a1);
        }
        l[j] = a0 + a1;
    }

    // ---- wave-local softmax over 512 keys (8 per lane)
    float m = l[0];
    #pragma unroll
    for (int j = 1; j < 8; ++j) m = fmaxf(m, l[j]);
    #pragma unroll
    for (int off = 32; off; off >>= 1) m = fmaxf(m, __shfl_xor(m, off));
    float e[8], s = 0.f;
    #pragma unroll
    for (int j = 0; j < 8; ++j) { e[j] = exp2_f(l[j] - m); s += e[j]; }
    #pragma unroll
    for (int off = 32; off; off >>= 1) s += __shfl_xor(s, off);
    const float inv = 1.f / s;
    #pragma unroll
    for (int j = 0; j < 8; ++j) ex_t[64 * j + lane][w] = e[j] * inv;
    __syncthreads();

    // ---- phase 2: context. thread (dg, kp): 64 keys, 4 d's, 4 queries.
    const int dg = tid & 31;
    const int kp = tid >> 5;
    const float4* k4 = reinterpret_cast<const float4*>(
        keys + ((size_t)b * NK + kp * 64) * D) + dg;
    const float4* e4 = reinterpret_cast<const float4*>(&ex_t[0][0]) + kp * 64;
    float4 a0 = {0,0,0,0}, a1 = a0, a2 = a0, a3 = a0;
    #pragma unroll 8
    for (int kk = 0; kk < 64; ++kk) {
        float4 kv = k4[(size_t)kk * (D / 4)];
        float4 ev = e4[kk];
        fma4(a0, kv, ev.x);
        fma4(a1, kv, ev.y);
        fma4(a2, kv, ev.z);
        fma4(a3, kv, ev.w);
    }
    *reinterpret_cast<float4*>(&acc_s[kp][0][4 * dg]) = a0;
    *reinterpret_cast<float4*>(&acc_s[kp][1][4 * dg]) = a1;
    *reinterpret_cast<float4*>(&acc_s[kp][2][4 * dg]) = a2;
    *reinterpret_cast<float4*>(&acc_s[kp][3][4 * dg]) = a3;
    __syncthreads();

    // ---- reduce 8 partitions, write out. thread t -> float2 at flat offset 2t.
    const int o = 2 * tid;            // 0..510 over (g,d)
    const int g = o >> 7;
    const int d = o & 127;
    float2 r = {0.f, 0.f};
    #pragma unroll
    for (int p = 0; p < 8; ++p) {
        float2 v = *reinterpret_cast<const float2*>(&acc_s[p][g][d]);
        r.x += v.x; r.y += v.y;
    }
    *reinterpret_cast<float2*>(&outp[((size_t)b * NQ + q0 + g) * D + d]) = r;
}

extern "C" void kernel_launch(void* const* d_in, const int* in_sizes, int n_in,
                              void* d_out, int out_size, void* d_ws, size_t ws_size,
                              hipStream_t stream) {
    const float* keys    = (const float*)d_in[0];
    const float* queries = (const float*)d_in[1];
    const float* Wk      = (const float*)d_in[2];
    const float* Wq      = (const float*)d_in[3];
    const float* b1      = (const float*)d_in[4];
    const float* w2      = (const float*)d_in[5];
    // d_in[6] = b2: dropped (softmax shift-invariant)
    float* out = (float*)d_out;

    float* kh = (float*)d_ws;                    // B*NK*H floats (pre-scaled)
    float* qh = kh + (size_t)B * NK * H;         // B*NQ*H floats (pre-scaled)

    const int proj_blocks = (B * NK + B * NQ) / 8;   // 512
    proj_kernel<<<proj_blocks, 256, 0, stream>>>(keys, queries, Wk, Wq, b1, kh, qh);
    attend_kernel<<<B * NQ / G, 256, 0, stream>>>(keys, kh, qh, w2, out);
}

// Round 3
// 23.407 us; speedup vs baseline: 2.2158x; 1.3057x over previous
//
#include <hip/hip_runtime.h>

#define B 4
#define NQ 512
#define NK 512
#define D 128
#define H 32
#define G 4                              // queries per attend block
#define PS 2.8853900817779268f           // 2*log2(e)

__device__ __forceinline__ float rcp_f(float x)  { return __builtin_amdgcn_rcpf(x); }
__device__ __forceinline__ float exp2_f(float x) { return __builtin_amdgcn_exp2f(x); }

__device__ __forceinline__ void fma4(float4& a, const float4& v, float s) {
    a.x = fmaf(s, v.x, a.x);
    a.y = fmaf(s, v.y, a.y);
    a.z = fmaf(s, v.z, a.z);
    a.w = fmaf(s, v.w, a.w);
}

// kh_t[b][h][k] = PS*(keys[b,k,:].Wk[:,h] + b1[h])   (transposed for coalesced attend reads)
// qh[b][q][h]   = PS*(queries[b,q,:].Wq[:,h])
__global__ __launch_bounds__(256) void proj_kernel(
    const float* __restrict__ keys, const float* __restrict__ queries,
    const float* __restrict__ Wk, const float* __restrict__ Wq,
    const float* __restrict__ b1,
    float* __restrict__ kh_t, float* __restrict__ qh)
{
    __shared__ float xs[8][D];
    const int tid = threadIdx.x;
    const int r0 = blockIdx.x * 8;
    const bool is_q = (r0 >= B * NK);
    const float* __restrict__ X = is_q ? (queries + (size_t)(r0 - B * NK) * D)
                                       : (keys + (size_t)r0 * D);
    const float* __restrict__ W = is_q ? Wq : Wk;

    reinterpret_cast<float4*>(&xs[0][0])[tid] =
        reinterpret_cast<const float4*>(X)[tid];
    __syncthreads();

    const int lr = tid >> 5;
    const int h  = tid & 31;
    // 4 accumulators break the serial fma chain
    float a0 = 0.f, a1 = 0.f, a2 = 0.f, a3 = 0.f;
    const float4* x4 = reinterpret_cast<const float4*>(&xs[lr][0]);
    #pragma unroll
    for (int i = 0; i < D / 4; ++i) {
        float4 v = x4[i];                     // LDS broadcast within 32-lane group
        a0 = fmaf(v.x, W[(4 * i + 0) * H + h], a0);
        a1 = fmaf(v.y, W[(4 * i + 1) * H + h], a1);
        a2 = fmaf(v.z, W[(4 * i + 2) * H + h], a2);
        a3 = fmaf(v.w, W[(4 * i + 3) * H + h], a3);
    }
    float acc = (a0 + a1) + (a2 + a3);
    if (is_q) {
        const int rq = r0 - B * NK + lr;
        qh[(size_t)rq * H + h] = acc * PS;
    } else {
        const int r = r0 + lr;
        const int b = r >> 9;                 // / NK
        const int k = r & (NK - 1);
        kh_t[((size_t)b * H + h) * NK + k] = (acc + b1[h]) * PS;
    }
}

// One block per (b, group of G=4 queries). 256 threads = 4 waves, wave w owns query q0+w.
__global__ __launch_bounds__(256) void attend_kernel(
    const float* __restrict__ keys,
    const float* __restrict__ kh_t,   // [B][H][NK], pre-scaled, b1 folded in
    const float* __restrict__ qh,     // [B][NQ][H], pre-scaled
    const float* __restrict__ w2,
    float* __restrict__ outp)
{
    __shared__ float ex_t[G][NK];     // 8 KB, normalized softmax weights
    __shared__ float acc_s[8][G][D];  // 16 KB, per-k-partition context partials
    __shared__ float qv_s[G][H];
    __shared__ float w2_s[H];

    const int tid  = threadIdx.x;
    const int lane = tid & 63;
    const int w    = tid >> 6;
    const int b    = blockIdx.x >> 7;
    const int q0   = (blockIdx.x & 127) * G;

    if (lane < H) {
        qv_s[w][lane] = qh[((size_t)b * NQ + q0 + w) * H + lane];
        if (w == 0) w2_s[lane] = -PS * w2[lane];
    }
    __syncthreads();

    // ---- phase 1: logits (log2-domain, constant term dropped) for
    //      k = 4*lane + c (l[0..3]) and k = 256 + 4*lane + c (l[4..7])
    float l[8];
    #pragma unroll
    for (int j = 0; j < 8; ++j) l[j] = 0.f;
    const float* khb = kh_t + (size_t)b * H * NK;
    #pragma unroll 8
    for (int h = 0; h < H; ++h) {
        const float4 v0 = reinterpret_cast<const float4*>(khb + h * NK)[lane];
        const float4 v1 = reinterpret_cast<const float4*>(khb + h * NK + 256)[lane];
        const float qv = qv_s[w][h];          // LDS broadcast
        const float wp = w2_s[h];
        l[0] = fmaf(wp, rcp_f(1.f + exp2_f(qv + v0.x)), l[0]);
        l[1] = fmaf(wp, rcp_f(1.f + exp2_f(qv + v0.y)), l[1]);
        l[2] = fmaf(wp, rcp_f(1.f + exp2_f(qv + v0.z)), l[2]);
        l[3] = fmaf(wp, rcp_f(1.f + exp2_f(qv + v0.w)), l[3]);
        l[4] = fmaf(wp, rcp_f(1.f + exp2_f(qv + v1.x)), l[4]);
        l[5] = fmaf(wp, rcp_f(1.f + exp2_f(qv + v1.y)), l[5]);
        l[6] = fmaf(wp, rcp_f(1.f + exp2_f(qv + v1.z)), l[6]);
        l[7] = fmaf(wp, rcp_f(1.f + exp2_f(qv + v1.w)), l[7]);
    }

    // ---- wave-local softmax over 512 keys (8 per lane)
    float m = l[0];
    #pragma unroll
    for (int j = 1; j < 8; ++j) m = fmaxf(m, l[j]);
    #pragma unroll
    for (int off = 32; off; off >>= 1) m = fmaxf(m, __shfl_xor(m, off));
    float e[8], s = 0.f;
    #pragma unroll
    for (int j = 0; j < 8; ++j) { e[j] = exp2_f(l[j] - m); s += e[j]; }
    #pragma unroll
    for (int off = 32; off; off >>= 1) s += __shfl_xor(s, off);
    const float inv = 1.f / s;
    const float4 st0 = { e[0] * inv, e[1] * inv, e[2] * inv, e[3] * inv };
    const float4 st1 = { e[4] * inv, e[5] * inv, e[6] * inv, e[7] * inv };
    reinterpret_cast<float4*>(&ex_t[w][0])[lane]   = st0;   // contiguous, conflict-free
    reinterpret_cast<float4*>(&ex_t[w][256])[lane] = st1;
    __syncthreads();

    // ---- phase 2: context. thread (dg, kp): 64 keys, 4 d's, 4 queries;
    //      each keys element read exactly once per block, coalesced.
    const int dg = tid & 31;
    const int kp = tid >> 5;
    const float4* k4 = reinterpret_cast<const float4*>(
        keys + ((size_t)b * NK + kp * 64) * D) + dg;
    float4 a0 = {0,0,0,0}, a1 = a0, a2 = a0, a3 = a0;
    #pragma unroll 8
    for (int kk = 0; kk < 64; ++kk) {
        float4 kv = k4[(size_t)kk * (D / 4)];
        const int k = kp * 64 + kk;
        fma4(a0, kv, ex_t[0][k]);             // broadcast reads
        fma4(a1, kv, ex_t[1][k]);
        fma4(a2, kv, ex_t[2][k]);
        fma4(a3, kv, ex_t[3][k]);
    }
    *reinterpret_cast<float4*>(&acc_s[kp][0][4 * dg]) = a0;
    *reinterpret_cast<float4*>(&acc_s[kp][1][4 * dg]) = a1;
    *reinterpret_cast<float4*>(&acc_s[kp][2][4 * dg]) = a2;
    *reinterpret_cast<float4*>(&acc_s[kp][3][4 * dg]) = a3;
    __syncthreads();

    // ---- reduce 8 partitions, write out. thread t -> float2 at flat offset 2t.
    const int o = 2 * tid;            // 0..510 over (g,d)
    const int g = o >> 7;
    const int d = o & 127;
    float2 r = {0.f, 0.f};
    #pragma unroll
    for (int p = 0; p < 8; ++p) {
        float2 v = *reinterpret_cast<const float2*>(&acc_s[p][g][d]);
        r.x += v.x; r.y += v.y;
    }
    *reinterpret_cast<float2*>(&outp[((size_t)b * NQ + q0 + g) * D + d]) = r;
}

extern "C" void kernel_launch(void* const* d_in, const int* in_sizes, int n_in,
                              void* d_out, int out_size, void* d_ws, size_t ws_size,
                              hipStream_t stream) {
    const float* keys    = (const float*)d_in[0];
    const float* queries = (const float*)d_in[1];
    const float* Wk      = (const float*)d_in[2];
    const float* Wq      = (const float*)d_in[3];
    const float* b1      = (const float*)d_in[4];
    const float* w2      = (const float*)d_in[5];
    // d_in[6] = b2: dropped (softmax shift-invariant)
    float* out = (float*)d_out;

    float* kh_t = (float*)d_ws;                    // B*H*NK floats (transposed, pre-scaled)
    float* qh   = kh_t + (size_t)B * H * NK;       // B*NQ*H floats (pre-scaled)

    const int proj_blocks = (B * NK + B * NQ) / 8;   // 512
    proj_kernel<<<proj_blocks, 256, 0, stream>>>(keys, queries, Wk, Wq, b1, kh_t, qh);
    attend_kernel<<<B * NQ / G, 256, 0, stream>>>(keys, kh_t, qh, w2, out);
}